// Round 1
// baseline (5372.949 us; speedup 1.0000x reference)
//
#include <hip/hip_runtime.h>
#include <hip/hip_bf16.h>
#include <math.h>

#define T_TOK 4096
#define H_DIM 2048
#define NH 16
#define NKV 8
#define HD 128
#define QS (NH * HD)        // 2048
#define KVS (NKV * HD)      // 1024
#define QKV_W (QS + 2*KVS)  // 4096
#define SCALE 0.08838834764831845f   // 128^-0.5
#define EPS 1e-6f

// ---------------- GEMM: C[M,N] = A[M,K] @ B[K,N], fp32, row-major ----------
__global__ __launch_bounds__(256) void gemm_f32(const float* __restrict__ A, int lda,
                                                const float* __restrict__ B, int ldb,
                                                float* __restrict__ C, int ldc,
                                                int M, int N, int K) {
    __shared__ float sA[16][68];   // [k][m], pad 68 keeps rows 16B-aligned
    __shared__ float sB[16][68];   // [k][n]
    const int tid = threadIdx.x;
    const int tx = tid & 15, ty = tid >> 4;
    const int bm = blockIdx.y * 64, bn = blockIdx.x * 64;
    float acc[4][4] = {};
    for (int k0 = 0; k0 < K; k0 += 16) {
        #pragma unroll
        for (int i = 0; i < 4; ++i) {
            int ml = i * 16 + ty;
            sA[tx][ml] = A[(size_t)(bm + ml) * lda + k0 + tx];
        }
        #pragma unroll
        for (int i = 0; i < 4; ++i) {
            int kl = i * 4 + (tid >> 6);
            int nl = tid & 63;
            sB[kl][nl] = B[(size_t)(k0 + kl) * ldb + bn + nl];
        }
        __syncthreads();
        #pragma unroll
        for (int kk = 0; kk < 16; ++kk) {
            float4 av = *(const float4*)&sA[kk][ty * 4];
            float4 bv = *(const float4*)&sB[kk][tx * 4];
            float a[4] = {av.x, av.y, av.z, av.w};
            float b[4] = {bv.x, bv.y, bv.z, bv.w};
            #pragma unroll
            for (int i = 0; i < 4; ++i)
                #pragma unroll
                for (int j = 0; j < 4; ++j)
                    acc[i][j] += a[i] * b[j];
        }
        __syncthreads();
    }
    #pragma unroll
    for (int i = 0; i < 4; ++i) {
        float4 r = {acc[i][0], acc[i][1], acc[i][2], acc[i][3]};
        *(float4*)&C[(size_t)(bm + ty * 4 + i) * ldc + bn + tx * 4] = r;
    }
}

// ------------- per-head RMSNorm + RoPE on q (16 heads) and k (8 heads) -----
__global__ __launch_bounds__(256) void rms_rope(float* __restrict__ qkv,
                                                const int* __restrict__ positions,
                                                const float* __restrict__ qw,
                                                const float* __restrict__ kw) {
    const int t = blockIdx.x;
    const int wave = threadIdx.x >> 6;
    const int lane = threadIdx.x & 63;
    const float pos = (float)positions[t];
    float* row = qkv + (size_t)t * QKV_W;
    // heads 0..15 = q, 16..23 = k; v untouched
    for (int h = wave; h < NH + NKV; h += 4) {
        float* x = row + h * HD;
        const float* w = (h < NH) ? qw : kw;
        float x1 = x[lane];
        float x2 = x[lane + 64];
        float ss = x1 * x1 + x2 * x2;
        #pragma unroll
        for (int off = 32; off > 0; off >>= 1) ss += __shfl_xor(ss, off, 64);
        float r = rsqrtf(ss * (1.0f / 128.0f) + EPS);
        float n1 = x1 * r * w[lane];
        float n2 = x2 * r * w[lane + 64];
        // neox rotate-half: pair (d, d+64), inv_freq = 1e6^(-d/64)
        float inv_freq = powf(1000000.0f, -(float)lane / 64.0f);
        float ang = pos * inv_freq;
        float s, c;
        sincosf(ang, &s, &c);
        x[lane]      = n1 * c - n2 * s;
        x[lane + 64] = n2 * c + n1 * s;
    }
}

// ---------------- causal GQA flash attention (fp32) ------------------------
// grid: (T/32 q-tiles, NH heads); block: 256 threads
// writes output into the q-region of qkv (cols h*128..h*128+127) — safe:
// that region is only ever read (as Q) by this same block, before the write.
__global__ __launch_bounds__(256) void attn(float* __restrict__ qkv) {
    __shared__ float Q[32][132];
    __shared__ float Kt[32][132];
    __shared__ float Vt[32][132];
    __shared__ float P[32][33];
    __shared__ float Mrow[32], Lrow[32], Alpha[32];

    const int h  = blockIdx.y;
    const int kv = h >> 1;                       // G = 2
    const int qt = (int)gridDim.x - 1 - (int)blockIdx.x;  // longest blocks first
    const int tid = threadIdx.x;
    const int t0 = qt * 32;

    for (int i = tid; i < 32 * 128; i += 256) {
        int r = i >> 7, d = i & 127;
        Q[r][d] = qkv[(size_t)(t0 + r) * QKV_W + h * HD + d] * SCALE;
    }
    if (tid < 32) { Mrow[tid] = -1e30f; Lrow[tid] = 0.0f; }

    float o[16] = {};
    const int orow = tid >> 3;       // 0..31
    const int dsub = tid & 7;        // dim d = dsub + 8*k

    const int nkt = qt + 1;
    for (int st = 0; st < nkt; ++st) {
        const int s0 = st * 32;
        for (int i = tid; i < 32 * 128; i += 256) {
            int r = i >> 7, d = i & 127;
            const float* src = qkv + (size_t)(s0 + r) * QKV_W;
            Kt[r][d] = src[QS + kv * HD + d];
            Vt[r][d] = src[QS + KVS + kv * HD + d];
        }
        __syncthreads();

        // scores: thread -> row si = tid/8, cols sj + 8*jj (bank-conflict-free)
        const int si = tid >> 3;
        const int sj = tid & 7;
        float sc[4] = {};
        for (int d = 0; d < 128; d += 4) {
            float4 qv = *(const float4*)&Q[si][d];
            #pragma unroll
            for (int jj = 0; jj < 4; ++jj) {
                float4 k4 = *(const float4*)&Kt[sj + 8 * jj][d];
                sc[jj] += qv.x * k4.x + qv.y * k4.y + qv.z * k4.z + qv.w * k4.w;
            }
        }
        #pragma unroll
        for (int jj = 0; jj < 4; ++jj) {
            int s_g = s0 + sj + 8 * jj;
            int t_g = t0 + si;
            P[si][sj + 8 * jj] = (s_g <= t_g) ? sc[jj] : -1e30f;
        }
        __syncthreads();

        // online softmax, one thread per row
        if (tid < 32) {
            float m_old = Mrow[tid];
            float m = m_old;
            #pragma unroll 8
            for (int j = 0; j < 32; ++j) m = fmaxf(m, P[tid][j]);
            float l_add = 0.0f;
            #pragma unroll 8
            for (int j = 0; j < 32; ++j) {
                float p = __expf(P[tid][j] - m);
                P[tid][j] = p;
                l_add += p;
            }
            float alpha = __expf(m_old - m);
            Mrow[tid] = m;
            Lrow[tid] = Lrow[tid] * alpha + l_add;
            Alpha[tid] = alpha;
        }
        __syncthreads();

        // PV: thread -> (row orow, dims dsub + 8*k)
        float a = Alpha[orow];
        #pragma unroll
        for (int k = 0; k < 16; ++k) o[k] *= a;
        for (int j = 0; j < 32; ++j) {
            float p = P[orow][j];
            #pragma unroll
            for (int k = 0; k < 16; ++k) o[k] += p * Vt[j][dsub + 8 * k];
        }
        __syncthreads();
    }

    const float linv = 1.0f / Lrow[orow];
    float* dst = qkv + (size_t)(t0 + orow) * QKV_W + h * HD;
    #pragma unroll
    for (int k = 0; k < 16; ++k) dst[dsub + 8 * k] = o[k] * linv;
}

extern "C" void kernel_launch(void* const* d_in, const int* in_sizes, int n_in,
                              void* d_out, int out_size, void* d_ws, size_t ws_size,
                              hipStream_t stream) {
    const int*   positions = (const int*)d_in[0];
    const float* hidden    = (const float*)d_in[1];
    const float* w_qkv     = (const float*)d_in[2];
    const float* w_o       = (const float*)d_in[3];
    const float* q_norm_w  = (const float*)d_in[4];
    const float* k_norm_w  = (const float*)d_in[5];
    float* out = (float*)d_out;
    float* qkv = (float*)d_ws;   // [T, 4096] fp32 = 64 MB

    // 1) QKV projection
    dim3 g1(QKV_W / 64, T_TOK / 64);
    gemm_f32<<<g1, 256, 0, stream>>>(hidden, H_DIM, w_qkv, QKV_W, qkv, QKV_W,
                                     T_TOK, QKV_W, H_DIM);
    // 2) per-head RMSNorm + RoPE (in place on q,k)
    rms_rope<<<T_TOK, 256, 0, stream>>>(qkv, positions, q_norm_w, k_norm_w);
    // 3) causal GQA attention; output overwrites q-region of qkv
    attn<<<dim3(T_TOK / 32, NH), 256, 0, stream>>>(qkv);
    // 4) output projection
    dim3 g2(H_DIM / 64, T_TOK / 64);
    gemm_f32<<<g2, 256, 0, stream>>>(qkv, QKV_W, w_o, H_DIM, out, H_DIM,
                                     T_TOK, H_DIM, H_DIM);
}

// Round 2
// 626.686 us; speedup vs baseline: 8.5736x; 8.5736x over previous
//
#include <hip/hip_runtime.h>
#include <hip/hip_bf16.h>
#include <math.h>

#define T_TOK 4096
#define H_DIM 2048
#define NH 16
#define NKV 8
#define HD 128
#define QS (NH * HD)        // 2048
#define KVS (NKV * HD)      // 1024
#define QKV_W (QS + 2*KVS)  // 4096
#define SCALE 0.08838834764831845f   // 128^-0.5
#define EPS 1e-6f

typedef short short8 __attribute__((ext_vector_type(8)));
typedef float floatx4 __attribute__((ext_vector_type(4)));
typedef unsigned short ushort4v __attribute__((ext_vector_type(4)));

__device__ __forceinline__ unsigned short f2bf(float f) {
    unsigned int u = __float_as_uint(f);
    unsigned int r = (u + 0x7FFFu + ((u >> 16) & 1u)) >> 16;   // RNE
    return (unsigned short)r;
}
__device__ __forceinline__ float bf2f(unsigned short u) {
    unsigned int v = ((unsigned int)u) << 16;
    return __uint_as_float(v);
}

// ================= MFMA GEMM: C[M,N] = A[M,K] @ B[K,N] =====================
// A: f32 or bf16 (template); B: f32 (cast to bf16 in staging); C: f32 or bf16.
// block 256 = 4 waves (2x2), tile 128x128, BK=32.
template<bool A_BF16, bool C_BF16>
__global__ __launch_bounds__(256, 2) void gemm_mfma(const void* __restrict__ Aptr, int lda,
                                                    const float* __restrict__ B, int ldb,
                                                    void* __restrict__ Cptr, int ldc,
                                                    int K) {
    __shared__ unsigned short As[128][56];   // [m][k], stride 56: 16B-aligned rows, 2-way max
    __shared__ unsigned short Bs[128][56];   // [n][k] (B transposed into k-contiguous)
    const int tid  = threadIdx.x;
    const int wave = tid >> 6, lane = tid & 63;
    const int quad = lane >> 4, l16 = lane & 15;
    const int wm = wave >> 1, wn = wave & 1;
    const int bm = blockIdx.y * 128, bn = blockIdx.x * 128;

    // B staging assignment: n0 = tid&31 (+32*nn), kr = (tid>>5)*4
    const int bn0 = tid & 31, bkr = (tid >> 5) * 4;

    floatx4 acc[4][4] = {};
    for (int k0 = 0; k0 < K; k0 += 32) {
        // ---- stage A: 128 rows x 32 k (8-elem chunks; 512 chunks, 2/thread)
        #pragma unroll
        for (int i = 0; i < 2; ++i) {
            int c = tid + 256 * i;
            int row = c >> 2, off = (c & 3) * 8;
            short8 t;
            if (A_BF16) {
                const unsigned short* src = (const unsigned short*)Aptr + (size_t)(bm + row) * lda + k0 + off;
                t = *(const short8*)src;
            } else {
                const float* src = (const float*)Aptr + (size_t)(bm + row) * lda + k0 + off;
                float4 v0 = *(const float4*)src;
                float4 v1 = *(const float4*)(src + 4);
                t[0] = (short)f2bf(v0.x); t[1] = (short)f2bf(v0.y);
                t[2] = (short)f2bf(v0.z); t[3] = (short)f2bf(v0.w);
                t[4] = (short)f2bf(v1.x); t[5] = (short)f2bf(v1.y);
                t[6] = (short)f2bf(v1.z); t[7] = (short)f2bf(v1.w);
            }
            *(short8*)&As[row][off] = t;
        }
        // ---- stage B transposed: Bs[n][k]; scalar coalesced loads, b64 writes
        {
            float bval[4][4];   // [nn][kk]
            #pragma unroll
            for (int kk = 0; kk < 4; ++kk)
                #pragma unroll
                for (int nn = 0; nn < 4; ++nn)
                    bval[nn][kk] = B[(size_t)(k0 + bkr + kk) * ldb + bn + bn0 + 32 * nn];
            #pragma unroll
            for (int nn = 0; nn < 4; ++nn) {
                ushort4v p;
                p[0] = f2bf(bval[nn][0]); p[1] = f2bf(bval[nn][1]);
                p[2] = f2bf(bval[nn][2]); p[3] = f2bf(bval[nn][3]);
                *(ushort4v*)&Bs[bn0 + 32 * nn][bkr] = p;
            }
        }
        __syncthreads();
        // ---- MFMA: 8 ds_read_b128 + 16 MFMA
        short8 a[4], b[4];
        #pragma unroll
        for (int mi = 0; mi < 4; ++mi)
            a[mi] = *(const short8*)&As[wm * 64 + mi * 16 + l16][quad * 8];
        #pragma unroll
        for (int ni = 0; ni < 4; ++ni)
            b[ni] = *(const short8*)&Bs[wn * 64 + ni * 16 + l16][quad * 8];
        #pragma unroll
        for (int mi = 0; mi < 4; ++mi)
            #pragma unroll
            for (int ni = 0; ni < 4; ++ni)
                acc[mi][ni] = __builtin_amdgcn_mfma_f32_16x16x32_bf16(a[mi], b[ni], acc[mi][ni], 0, 0, 0);
        __syncthreads();
    }
    // ---- epilogue
    #pragma unroll
    for (int mi = 0; mi < 4; ++mi)
        #pragma unroll
        for (int ni = 0; ni < 4; ++ni)
            #pragma unroll
            for (int r = 0; r < 4; ++r) {
                int row = bm + wm * 64 + mi * 16 + quad * 4 + r;
                int col = bn + wn * 64 + ni * 16 + l16;
                if (C_BF16)
                    ((unsigned short*)Cptr)[(size_t)row * ldc + col] = f2bf(acc[mi][ni][r]);
                else
                    ((float*)Cptr)[(size_t)row * ldc + col] = acc[mi][ni][r];
            }
}

// ============ per-head RMSNorm + RoPE on bf16 qkv (q: 16 heads, k: 8) ======
__global__ __launch_bounds__(256) void rms_rope_bf16(unsigned short* __restrict__ qkv,
                                                     const int* __restrict__ positions,
                                                     const float* __restrict__ qw,
                                                     const float* __restrict__ kw) {
    const int t = blockIdx.x;
    const int wave = threadIdx.x >> 6;
    const int lane = threadIdx.x & 63;
    const float pos = (float)positions[t];
    unsigned short* row = qkv + (size_t)t * QKV_W;
    const float inv_freq = powf(1000000.0f, -(float)lane / 64.0f);
    float sv, cv;
    sincosf(pos * inv_freq, &sv, &cv);
    for (int h = wave; h < NH + NKV; h += 4) {
        unsigned short* x = row + h * HD;
        const float* w = (h < NH) ? qw : kw;
        float x1 = bf2f(x[lane]);
        float x2 = bf2f(x[lane + 64]);
        float ss = x1 * x1 + x2 * x2;
        #pragma unroll
        for (int off = 32; off > 0; off >>= 1) ss += __shfl_xor(ss, off, 64);
        float r = rsqrtf(ss * (1.0f / 128.0f) + EPS);
        float n1 = x1 * r * w[lane];
        float n2 = x2 * r * w[lane + 64];
        x[lane]      = f2bf(n1 * cv - n2 * sv);
        x[lane + 64] = f2bf(n2 * cv + n1 * sv);
    }
}

// ================= MFMA causal GQA flash attention =========================
// grid (32 qtiles, 16 heads), block 256 = 4 waves. QTILE=128 rows, 64 KV/step.
// Q in registers; K LDS [64][136]; V transposed LDS [128][72]; P LDS [128][72].
// Output (bf16) overwrites q-region of qkv — block-local region only.
__global__ __launch_bounds__(256, 2) void attn_mfma(unsigned short* __restrict__ qkv) {
    __shared__ unsigned short Ks[64][136];
    __shared__ unsigned short Vt[128][72];
    __shared__ unsigned short Ps[128][72];
    const int h = blockIdx.y, kv = h >> 1;
    const int qt = (int)gridDim.x - 1 - (int)blockIdx.x;   // longest first
    const int tid = threadIdx.x;
    const int wave = tid >> 6, lane = tid & 63;
    const int quad = lane >> 4, l16 = lane & 15;
    const int t0 = qt * 128;

    // Q fragments in registers: rows t0 + wave*32 + rt*16 + l16
    short8 qf[2][4];
    #pragma unroll
    for (int rt = 0; rt < 2; ++rt)
        #pragma unroll
        for (int ks = 0; ks < 4; ++ks) {
            int rowg = t0 + wave * 32 + rt * 16 + l16;
            int col = h * HD + ks * 32 + quad * 8;
            qf[rt][ks] = *(const short8*)&qkv[(size_t)rowg * QKV_W + col];
        }

    float m_s[2][4], l_s[2][4];
    #pragma unroll
    for (int rt = 0; rt < 2; ++rt)
        #pragma unroll
        for (int r = 0; r < 4; ++r) { m_s[rt][r] = -1e30f; l_s[rt][r] = 0.0f; }
    floatx4 oacc[2][8] = {};

    // V staging assignment: d0 = (tid>>4)*8, sv = (tid&15)*4
    const int vd0 = (tid >> 4) * 8, vsv = (tid & 15) * 4;

    const int nst = 2 * qt + 2;
    for (int st = 0; st < nst; ++st) {
        const int s0 = st * 64;
        // ---- stage K: 64 rows x 128 (16B chunks, 4/thread, coalesced)
        #pragma unroll
        for (int i = 0; i < 4; ++i) {
            int c = tid + 256 * i;
            int row = c >> 4, off = (c & 15) * 8;
            *(short8*)&Ks[row][off] =
                *(const short8*)&qkv[(size_t)(s0 + row) * QKV_W + QS + kv * HD + off];
        }
        // ---- stage V transposed: Vt[d][s]
        {
            short8 vv[4];
            #pragma unroll
            for (int ss = 0; ss < 4; ++ss)
                vv[ss] = *(const short8*)&qkv[(size_t)(s0 + vsv + ss) * QKV_W + QS + KVS + kv * HD + vd0];
            #pragma unroll
            for (int dd = 0; dd < 8; ++dd) {
                ushort4v p;
                p[0] = (unsigned short)vv[0][dd]; p[1] = (unsigned short)vv[1][dd];
                p[2] = (unsigned short)vv[2][dd]; p[3] = (unsigned short)vv[3][dd];
                *(ushort4v*)&Vt[vd0 + dd][vsv] = p;
            }
        }
        __syncthreads();

        // ---- S = Q K^T (32 MFMA / wave)
        floatx4 sacc[2][4] = {};
        #pragma unroll
        for (int ks = 0; ks < 4; ++ks) {
            short8 bfr[4];
            #pragma unroll
            for (int ct = 0; ct < 4; ++ct)
                bfr[ct] = *(const short8*)&Ks[ct * 16 + l16][ks * 32 + quad * 8];
            #pragma unroll
            for (int rt = 0; rt < 2; ++rt)
                #pragma unroll
                for (int ct = 0; ct < 4; ++ct)
                    sacc[rt][ct] = __builtin_amdgcn_mfma_f32_16x16x32_bf16(qf[rt][ks], bfr[ct], sacc[rt][ct], 0, 0, 0);
        }

        // ---- scale + causal mask + online softmax (per-row, quad-local)
        #pragma unroll
        for (int rt = 0; rt < 2; ++rt) {
            #pragma unroll
            for (int ct = 0; ct < 4; ++ct)
                #pragma unroll
                for (int r = 0; r < 4; ++r) {
                    float v = sacc[rt][ct][r] * SCALE;
                    int sg = s0 + ct * 16 + l16;
                    int tg = t0 + wave * 32 + rt * 16 + quad * 4 + r;
                    sacc[rt][ct][r] = (sg <= tg) ? v : -1e30f;
                }
            #pragma unroll
            for (int r = 0; r < 4; ++r) {
                float mx = fmaxf(fmaxf(sacc[rt][0][r], sacc[rt][1][r]),
                                 fmaxf(sacc[rt][2][r], sacc[rt][3][r]));
                mx = fmaxf(mx, __shfl_xor(mx, 1, 64));
                mx = fmaxf(mx, __shfl_xor(mx, 2, 64));
                mx = fmaxf(mx, __shfl_xor(mx, 4, 64));
                mx = fmaxf(mx, __shfl_xor(mx, 8, 64));
                float mold = m_s[rt][r];
                float mnew = fmaxf(mold, mx);
                float alpha = __expf(mold - mnew);
                float lsum = 0.0f;
                #pragma unroll
                for (int ct = 0; ct < 4; ++ct) {
                    float p = __expf(sacc[rt][ct][r] - mnew);
                    sacc[rt][ct][r] = p;
                    lsum += p;
                }
                lsum += __shfl_xor(lsum, 1, 64);
                lsum += __shfl_xor(lsum, 2, 64);
                lsum += __shfl_xor(lsum, 4, 64);
                lsum += __shfl_xor(lsum, 8, 64);
                l_s[rt][r] = l_s[rt][r] * alpha + lsum;
                m_s[rt][r] = mnew;
                #pragma unroll
                for (int dct = 0; dct < 8; ++dct)
                    oacc[rt][dct][r] *= alpha;
                // P to LDS (bf16, C-layout row)
                int prow = wave * 32 + rt * 16 + quad * 4 + r;
                #pragma unroll
                for (int ct = 0; ct < 4; ++ct)
                    Ps[prow][ct * 16 + l16] = f2bf(sacc[rt][ct][r]);
            }
        }
        // no barrier needed: Ps rows are written and read by the SAME wave;
        // compiler orders same-array LDS ops via lgkmcnt.

        // ---- O += P V (32 MFMA / wave)
        #pragma unroll
        for (int ks2 = 0; ks2 < 2; ++ks2) {
            short8 af[2];
            #pragma unroll
            for (int rt = 0; rt < 2; ++rt)
                af[rt] = *(const short8*)&Ps[wave * 32 + rt * 16 + l16][ks2 * 32 + quad * 8];
            #pragma unroll
            for (int dct = 0; dct < 8; ++dct) {
                short8 bfr = *(const short8*)&Vt[dct * 16 + l16][ks2 * 32 + quad * 8];
                #pragma unroll
                for (int rt = 0; rt < 2; ++rt)
                    oacc[rt][dct] = __builtin_amdgcn_mfma_f32_16x16x32_bf16(af[rt], bfr, oacc[rt][dct], 0, 0, 0);
            }
        }
        __syncthreads();   // before next step overwrites Ks/Vt
    }

    // ---- epilogue: normalize, bf16, overwrite q-region
    #pragma unroll
    for (int rt = 0; rt < 2; ++rt)
        #pragma unroll
        for (int r = 0; r < 4; ++r) {
            float linv = 1.0f / l_s[rt][r];
            int rowg = t0 + wave * 32 + rt * 16 + quad * 4 + r;
            #pragma unroll
            for (int dct = 0; dct < 8; ++dct) {
                int col = h * HD + dct * 16 + l16;
                qkv[(size_t)rowg * QKV_W + col] = f2bf(oacc[rt][dct][r] * linv);
            }
        }
}

extern "C" void kernel_launch(void* const* d_in, const int* in_sizes, int n_in,
                              void* d_out, int out_size, void* d_ws, size_t ws_size,
                              hipStream_t stream) {
    const int*   positions = (const int*)d_in[0];
    const float* hidden    = (const float*)d_in[1];
    const float* w_qkv     = (const float*)d_in[2];
    const float* w_o       = (const float*)d_in[3];
    const float* q_norm_w  = (const float*)d_in[4];
    const float* k_norm_w  = (const float*)d_in[5];
    float* out = (float*)d_out;
    unsigned short* qkvb = (unsigned short*)d_ws;   // [4096, 4096] bf16 = 32 MB

    // 1) QKV projection (f32 in, bf16 out)
    gemm_mfma<false, true><<<dim3(QKV_W / 128, T_TOK / 128), 256, 0, stream>>>(
        hidden, H_DIM, w_qkv, QKV_W, qkvb, QKV_W, H_DIM);
    // 2) RMSNorm + RoPE in place (bf16)
    rms_rope_bf16<<<T_TOK, 256, 0, stream>>>(qkvb, positions, q_norm_w, k_norm_w);
    // 3) flash attention (bf16 MFMA), writes into q-region
    attn_mfma<<<dim3(T_TOK / 128, NH), 256, 0, stream>>>(qkvb);
    // 4) output projection (bf16 A, f32 B, f32 out)
    gemm_mfma<true, false><<<dim3(H_DIM / 128, T_TOK / 128), 256, 0, stream>>>(
        qkvb, QKV_W, w_o, H_DIM, out, H_DIM, QS);
}